// Round 7
// baseline (155.883 us; speedup 1.0000x reference)
//
#include <hip/hip_runtime.h>
#include <cstddef>

// Voxel encoder: B=2, N=16384, G=512 voxels x K=32 pts, d=128, S=2 layers.
// Round 20: RECOVERY from r19 correctness failure (absmax 4.375). r19
// bundled (a) v_cvt_pk_bf16_f32 via inline asm and (b) layer-invariant
// quant-index precompute. (a) is the prime suspect (packing/rounding
// mismatch vs manual RTNE f2bf; guide m240 warns against hand-written
// cvt_pk). This round: REVERT all pk2bf -> proven f2bf; KEEP idx_s
// precompute (pure integer refactor of identical math, off the serialized
// scores critical path). Base structure = r18 (47us proven).
// RULE (r8/r10): never force min-waves>2. RULE (r17): <=2 B-frag tiles +
// <=2 acc chains in phase A. RULE (r16): one voxel per block.
// RULE (r19): no inline-asm cvt_pk -- manual f2bf only.

#define D_   128
#define VSF  0.25f
#define QSF  0.01f
#define LQ   50
#define G_   512
#define KP   32
#define BB   2
#define NP   16384
#define MT   32768
#define SCALE 0.08838834764831845f   // 1/sqrt(128)
#define NT_ALL 34           // 24 qkv tiles + 10 dk tiles (cols 0..543)
#define FRAG_S (NT_ALL * 4 * 64 * 8)   // ushorts per layer frag buffer

using short8 = __attribute__((ext_vector_type(8))) short;
using f32x4  = __attribute__((ext_vector_type(4))) float;

__device__ inline unsigned short f2bf(float x) {
  unsigned u = __builtin_bit_cast(unsigned, x);
  u += 0x7fffu + ((u >> 16) & 1u);      // round-to-nearest-even
  return (unsigned short)(u >> 16);
}
__device__ inline float bu(unsigned short h) {
  return __builtin_bit_cast(float, (unsigned)h << 16);
}
__device__ inline short8 as_short8(uint4 v) {
  union { uint4 u; short8 s; } x; x.u = v; return x.s;
}

// ---------------------------------------------------------------------------
// prep_all: all weight preprocessing in ONE launch. 370 blocks x 64 threads.
// (unchanged from r18)
// ---------------------------------------------------------------------------
__global__ __launch_bounds__(64) void prep_all(
    const float* __restrict__ qkv_w, const float* __restrict__ trans_w,
    const float* __restrict__ qkv_b,
    const float* __restrict__ tbl_x, const float* __restrict__ tbl_y,
    const float* __restrict__ tbl_z,
    unsigned short* __restrict__ allfrag,
    unsigned short* __restrict__ transfrag,
    float* __restrict__ bc)
{
  __shared__ __align__(16) float As[32][132];   // Wk rows   (Wf branch only)
  __shared__ __align__(16) float Ts[16][132];   // T columns (Wf branch only)

  const int blk  = blockIdx.x;
  const int lane = threadIdx.x;

  if (blk >= 192 && blk < 272) {
    // ---- Wf frag blocks: compute Wf[m][c] = sum_e Wk[m][e] * T[e][c] ----
    const int s = (blk - 192) / 40, r = (blk - 192) - s * 40;
    const int snt = r >> 2, ks = r & 3;
    const float* Abase = qkv_w + (size_t)s * 128 * 384 + 128;
    for (int i = lane; i < 32 * 32; i += 64) {
      const int m = i >> 5, q = i & 31;
      float4 v = *(const float4*)(Abase + (size_t)(ks * 32 + m) * 384 + q * 4);
      *(float4*)&As[m][q * 4] = v;
    }
    for (int i = lane; i < 16 * 32; i += 64) {
      const int cl = i >> 5, q = i & 31;
      const int c = snt * 16 + cl;
      float4 v = {0.f, 0.f, 0.f, 0.f};
      if (c < 150) {
        const int axis = c / 50, l = c - axis * 50;
        const float* tb = (axis == 0 ? tbl_x : (axis == 1 ? tbl_y : tbl_z));
        v = *(const float4*)(tb + (((size_t)s * 3 + 1) * LQ + l) * D_ + q * 4);
      }
      *(float4*)&Ts[cl][q * 4] = v;
    }
    __syncthreads();
    const int cl = lane & 15, mb = (lane >> 4) * 8;
    float acc[8];
    #pragma unroll
    for (int m = 0; m < 8; m++) acc[m] = 0.f;
    for (int e = 0; e < 128; e += 4) {
      float4 tv = *(const float4*)&Ts[cl][e];
      #pragma unroll
      for (int m = 0; m < 8; m++) {
        float4 av = *(const float4*)&As[mb + m][e];
        acc[m] += av.x * tv.x;
        acc[m] += av.y * tv.y;
        acc[m] += av.z * tv.z;
        acc[m] += av.w * tv.w;
      }
    }
    unsigned v[4];
    #pragma unroll
    for (int h = 0; h < 4; h++)
      v[h] = f2bf(acc[2 * h]) | ((unsigned)f2bf(acc[2 * h + 1]) << 16);
    uint4 o = {v[0], v[1], v[2], v[3]};
    unsigned short* dst = allfrag + (size_t)s * FRAG_S;
    const int dstidx = (24 + snt) * 4 + ks;
    *(uint4*)(dst + ((size_t)dstidx * 64 + lane) * 8) = o;
    return;
  }

  if (blk >= 368) {
    // ---- bc: [0,384) qkv_b copy; [384,544) = bk @ T from tables ----
    const int s = blk - 368;
    for (int c = lane; c < 544; c += 64) {
      float v;
      if (c < 384) {
        v = qkv_b[s * 384 + c];
      } else {
        const int cc = c - 384;
        float a = 0.f;
        if (cc < 150) {
          const int axis = cc / 50, l = cc - axis * 50;
          const float* tb = (axis == 0 ? tbl_x : (axis == 1 ? tbl_y : tbl_z));
          const float* tr = tb + (((size_t)s * 3 + 1) * LQ + l) * D_;
          const float* bk = qkv_b + (size_t)s * 384 + 128;
          #pragma unroll 4
          for (int e = 0; e < 128; e++) a += bk[e] * tr[e];
        }
        v = a;
      }
      bc[s * 544 + c] = v;
    }
    return;
  }

  // ---- direct frag packing (qkv / trans weights) ----
  const float* B; int ldb, dstidx; unsigned short* dst; int kbase, n;
  if (blk < 192) {
    const int s = blk / 96, r = blk - s * 96;
    const int nt = r >> 2, ks = r & 3;
    B = qkv_w + (size_t)s * 128 * 384; ldb = 384;
    n = nt * 16 + (lane & 15);
    kbase = ks * 32 + ((lane >> 4) * 8);
    dst = allfrag + (size_t)s * FRAG_S;
    dstidx = nt * 4 + ks;
  } else {
    const int r = blk - 272;
    const int nt = r / 12, ks = r - nt * 12;
    B = trans_w; ldb = 128;
    n = nt * 16 + (lane & 15);
    kbase = ks * 32 + ((lane >> 4) * 8);
    dst = transfrag;
    dstidx = nt * 12 + ks;
  }
  unsigned v[4];
  #pragma unroll
  for (int h = 0; h < 4; h++) {
    const float x0 = B[(size_t)(kbase + 2 * h) * ldb + n];
    const float x1 = B[(size_t)(kbase + 2 * h + 1) * ldb + n];
    v[h] = f2bf(x0) | ((unsigned)f2bf(x1) << 16);
  }
  uint4 o = {v[0], v[1], v[2], v[3]};
  *(uint4*)(dst + ((size_t)dstidx * 64 + lane) * 8) = o;
}

// ---------------------------------------------------------------------------
// MEGA: one block (8 waves, 512 threads) per voxel; whole network per voxel.
// qk_s row (stride 424): q/f2 0:128 | k,then P 128:256 | dk 256:416.
// feats_s holds x0, then f1 after layer-0 PV. red/wmax/pooled alias sc_s.
// idx_s: precomputed layer-invariant quant indices (ix|iy<<6|iz<<12).
// ---------------------------------------------------------------------------
__global__ __launch_bounds__(512, 2) void mega(
    const float* __restrict__ inputs,
    const float* __restrict__ coords,
    const int*   __restrict__ groups,
    const unsigned short* __restrict__ allfrag,   // 2 x FRAG_S
    const float* __restrict__ bc,                 // 2 x 544
    const unsigned short* __restrict__ transfrag, // 8 nt x 12 ks
    const float* __restrict__ trans_b, const float* __restrict__ ln_g,
    const float* __restrict__ ln_b,
    float* __restrict__ out_all)
{
  __shared__ __align__(16) unsigned short feats_s[32][136];  // x0, then f1
  __shared__ __align__(16) unsigned short qk_s[32][424];     // q|k/P|dk; f2->q
  __shared__ __align__(16) unsigned short vT_s[128][40];     // V^T [f][j]
  __shared__ __align__(16) float sc_s[32 * 34];   // stride 34: <=2-way banks
  __shared__ float cs[32][4];
  __shared__ int idx_s[32][33];                   // packed quant indices
  // aliases into sc_s (scores dead after the last softmax):
  float (*red_s)[2][16][2] = (float (*)[2][16][2])sc_s;      // 2048 B
  float (*wmax_s)[128]     = (float (*)[128])(sc_s + 512);   // 1024 B
  float* pooled_s = sc_s;                                    // 512 B

  const int t   = threadIdx.x;
  const int bid = blockIdx.x;
  const int b   = bid >> 9;
  const int g   = bid & 511;
  const int wv = t >> 6, lane = t & 63, quad = lane >> 4, col = lane & 15;

  // ---- stage feats (gather + fp32->bf16): 16 thr/row, 8 elems each ----
  {
    const int p = t >> 4, sg = t & 15;
    const int pid = groups[(b << 14) + g * KP + p];
    const float* src = inputs + ((size_t)(b << 14) + (size_t)pid) * D_ + sg * 8;
    float4 a0 = *(const float4*)(src);
    float4 a1 = *(const float4*)(src + 4);
    uint4 o0;
    o0.x = f2bf(a0.x) | ((unsigned)f2bf(a0.y) << 16);
    o0.y = f2bf(a0.z) | ((unsigned)f2bf(a0.w) << 16);
    o0.z = f2bf(a1.x) | ((unsigned)f2bf(a1.y) << 16);
    o0.w = f2bf(a1.z) | ((unsigned)f2bf(a1.w) << 16);
    *(uint4*)&feats_s[p][sg * 8] = o0;
  }
  if (t < 32) {
    const int pid = groups[(b << 14) + g * KP + t];
    const float* cp = coords + ((size_t)(b << 14) + (size_t)pid) * 3;
    cs[t][0] = cp[0]; cs[t][1] = cp[1]; cs[t][2] = cp[2];
  }
  __syncthreads();

  // ---- precompute layer-invariant quant indices (2 pairs per thread) ----
  for (int pp = t; pp < 1024; pp += 512) {
    const int i = pp >> 5, j = pp & 31;
    const float dx = cs[i][0] - cs[j][0];
    const float dy = cs[i][1] - cs[j][1];
    const float dz = cs[i][2] - cs[j][2];
    int ix = (int)floorf((dx + VSF) / QSF);
    int iy = (int)floorf((dy + VSF) / QSF);
    int iz = (int)floorf((dz + VSF) / QSF);
    ix = ix < 0 ? 0 : (ix > 49 ? 49 : ix);
    iy = iy < 0 ? 0 : (iy > 49 ? 49 : iy);
    iz = iz < 0 ? 0 : (iz > 49 ? 49 : iz);
    idx_s[i][j] = ix | (iy << 6) | (iz << 12);
  }

  // ---- phase-A tile ranges: frag read once per block ----
  const int startsA[8] = {0, 5, 10, 14, 18, 22, 26, 30};
  const int cntsA[8]   = {5, 5, 4, 4, 4, 4, 4, 4};
  const int start = startsA[wv];
  const int cnt   = cntsA[wv];

  // persistent trans accumulators: wave wv owns output cols wv*16..wv*16+15
  f32x4 tacc[2];
  tacc[0] = (f32x4){0.f, 0.f, 0.f, 0.f};
  tacc[1] = (f32x4){0.f, 0.f, 0.f, 0.f};
  const uint4* tf = (const uint4*)transfrag + lane;

  for (int layer = 0; layer < 2; layer++) {
    const uint4* fr = (const uint4*)(allfrag + (size_t)layer * FRAG_S) + lane;
    const float* bcl = bc + layer * 544;

    // A-frags for BOTH row halves; layer 0: x0, layer 1: f1 (same buffer)
    uint4 avu[2][4];
    #pragma unroll
    for (int ks = 0; ks < 4; ks++) {
      avu[0][ks] = *(const uint4*)&feats_s[col][ks * 32 + quad * 8];
      avu[1][ks] = *(const uint4*)&feats_s[16 + col][ks * 32 + quad * 8];
    }

    // Phase A with depth-1 prefetch of next tile's B-frags (tail guarded)
    uint4 bvc[4];
    #pragma unroll
    for (int ks = 0; ks < 4; ks++) bvc[ks] = fr[(start * 4 + ks) * 64];

    for (int u = 0; u < cnt; u++) {
      const bool pf = (u + 1 < cnt);       // wave-uniform
      uint4 bvn[4];
      if (pf) {
        #pragma unroll
        for (int ks = 0; ks < 4; ks++)
          bvn[ks] = fr[((start + u + 1) * 4 + ks) * 64];
      }

      f32x4 a0 = (f32x4){0.f, 0.f, 0.f, 0.f};
      f32x4 a1 = (f32x4){0.f, 0.f, 0.f, 0.f};
      #pragma unroll
      for (int ks = 0; ks < 4; ks++) {
        short8 bv = as_short8(bvc[ks]);
        a0 = __builtin_amdgcn_mfma_f32_16x16x32_bf16(as_short8(avu[0][ks]), bv, a0, 0, 0, 0);
        a1 = __builtin_amdgcn_mfma_f32_16x16x32_bf16(as_short8(avu[1][ks]), bv, a1, 0, 0, 0);
      }
      const int nt = start + u;
      const int cc = nt * 16 + col;
      const float bsv = bcl[cc];
      if (cc >= 256 && cc < 384) {          // V tile -> vT_s[f][j], b64 x2
        const unsigned lo0 = f2bf(a0[0] + bsv) | ((unsigned)f2bf(a0[1] + bsv) << 16);
        const unsigned hi0 = f2bf(a0[2] + bsv) | ((unsigned)f2bf(a0[3] + bsv) << 16);
        uint2 w0 = {lo0, hi0};
        *(uint2*)&vT_s[cc - 256][quad * 4] = w0;
        const unsigned lo1 = f2bf(a1[0] + bsv) | ((unsigned)f2bf(a1[1] + bsv) << 16);
        const unsigned hi1 = f2bf(a1[2] + bsv) | ((unsigned)f2bf(a1[3] + bsv) << 16);
        uint2 w1 = {lo1, hi1};
        *(uint2*)&vT_s[cc - 256][16 + quad * 4] = w1;
      } else {
        const int ccol = (cc < 256) ? cc : cc - 128;   // dk -> 256..415
        #pragma unroll
        for (int reg = 0; reg < 4; reg++) {
          qk_s[quad * 4 + reg][ccol]      = f2bf(a0[reg] + bsv);
          qk_s[16 + quad * 4 + reg][ccol] = f2bf(a1[reg] + bsv);
        }
      }
      if (pf) {
        #pragma unroll
        for (int ks = 0; ks < 4; ks++) bvc[ks] = bvn[ks];
      }
    }
    // prefetch this layer's trans-chunk B-frags; the barrier's vmcnt drain
    // absorbs the latency.
    uint4 tgv[4];
    #pragma unroll
    for (int ks = 0; ks < 4; ks++) tgv[ks] = tf[(wv * 12 + layer * 4 + ks) * 64];
    __syncthreads();

    // scores via MFMA from LDS frags (waves 0..3)
    if (wv < 4) {
      const int ihalf = wv >> 1, jhalf = wv & 1;
      f32x4 sacc = {0.f, 0.f, 0.f, 0.f};
      #pragma unroll
      for (int ks = 0; ks < 4; ks++) {
        short8 qv = as_short8(*(const uint4*)&qk_s[ihalf * 16 + col][ks * 32 + quad * 8]);
        short8 kv = as_short8(*(const uint4*)&qk_s[jhalf * 16 + col][128 + ks * 32 + quad * 8]);
        sacc = __builtin_amdgcn_mfma_f32_16x16x32_bf16(qv, kv, sacc, 0, 0, 0);
      }
      const int j = jhalf * 16 + col;
      #pragma unroll
      for (int reg = 0; reg < 4; reg++) {
        const int i = ihalf * 16 + quad * 4 + reg;
        const int pk = idx_s[i][j];
        const int ix = pk & 63, iy = (pk >> 6) & 63, iz = pk >> 12;
        const unsigned short* dki = &qk_s[i][256];
        const float biasv = bu(dki[ix]) + bu(dki[50 + iy]) + bu(dki[100 + iz]);
        sc_s[i * 34 + j] = (sacc[reg] + biasv) * SCALE;
      }
    }
    // trans chunk (k-block = this layer's A operand), reusing live avu regs.
    // Waves 4..7 run this in their scores-idle window.
    #pragma unroll
    for (int ks = 0; ks < 4; ks++) {
      short8 bv = as_short8(tgv[ks]);
      tacc[0] = __builtin_amdgcn_mfma_f32_16x16x32_bf16(as_short8(avu[0][ks]), bv, tacc[0], 0, 0, 0);
      tacc[1] = __builtin_amdgcn_mfma_f32_16x16x32_bf16(as_short8(avu[1][ks]), bv, tacc[1], 0, 0, 0);
    }
    __syncthreads();

    // softmax: 8 threads per row (t<256); emit bf16 P over dead k cols 128..159
    if (t < 256) {
      const int p = t >> 3, sg = t & 7;
      float vals[4];
      float lm = -1e30f;
      #pragma unroll
      for (int u = 0; u < 4; u++) {
        vals[u] = sc_s[p * 34 + sg + u * 8];
        lm = fmaxf(lm, vals[u]);
      }
      lm = fmaxf(lm, __shfl_xor(lm, 1));
      lm = fmaxf(lm, __shfl_xor(lm, 2));
      lm = fmaxf(lm, __shfl_xor(lm, 4));
      float ls = 0.f;
      #pragma unroll
      for (int u = 0; u < 4; u++) { vals[u] = __expf(vals[u] - lm); ls += vals[u]; }
      ls += __shfl_xor(ls, 1);
      ls += __shfl_xor(ls, 2);
      ls += __shfl_xor(ls, 4);
      const float inv = 1.f / ls;
      #pragma unroll
      for (int u = 0; u < 4; u++)
        qk_s[p][128 + sg + u * 8] = f2bf(vals[u] * inv);
    }
    __syncthreads();

    // PV via MFMA: wave wv does mt=wv&1, ftiles (wv>>1)*2 + {0,1}.
    // layer 0 -> f1 overwrites feats_s; layer 1 -> f2 into qk_s cols 0..127.
    {
      const int mt = wv & 1, ftb = (wv >> 1) * 2;
      unsigned short* dst_base = (layer == 0) ? &feats_s[0][0] : &qk_s[0][0];
      const int dst_ld = (layer == 0) ? 136 : 424;
      short8 pv = as_short8(*(const uint4*)&qk_s[mt * 16 + col][128 + quad * 8]);
      #pragma unroll
      for (int u = 0; u < 2; u++) {
        const int ft = ftb + u;
        short8 vv = as_short8(*(const uint4*)&vT_s[ft * 16 + col][quad * 8]);
        f32x4 o = (f32x4){0.f, 0.f, 0.f, 0.f};
        o = __builtin_amdgcn_mfma_f32_16x16x32_bf16(pv, vv, o, 0, 0, 0);
        const int f = ft * 16 + col;
        #pragma unroll
        for (int reg = 0; reg < 4; reg++) {
          const int i = mt * 16 + quad * 4 + reg;
          dst_base[i * dst_ld + f] = f2bf(o[reg]);
        }
      }
    }
    __syncthreads();
  }

  // ---- trans GEMM tail: only the f2 chunk (ks 8..11) remains ----
  const int nt = wv;
  {
    uint4 gv[4];
    #pragma unroll
    for (int ks = 0; ks < 4; ks++) gv[ks] = tf[(nt * 12 + 8 + ks) * 64];
    #pragma unroll
    for (int ks = 0; ks < 4; ks++) {
      short8 bv = as_short8(gv[ks]);
      #pragma unroll
      for (int mt = 0; mt < 2; mt++) {
        short8 av = as_short8(*(const uint4*)&qk_s[mt * 16 + col][ks * 32 + quad * 8]);
        tacc[mt] = __builtin_amdgcn_mfma_f32_16x16x32_bf16(av, bv, tacc[mt], 0, 0, 0);
      }
    }
  }
  // bias + LN partial stats (16 cols per wave, both mtiles)
  const int c = nt * 16 + col;
  const float bsv = trans_b[c], gg = ln_g[c], lb = ln_b[c];
  float s[2][4], ssq[2][4];
  #pragma unroll
  for (int mt = 0; mt < 2; mt++)
    #pragma unroll
    for (int reg = 0; reg < 4; reg++) {
      const float v = tacc[mt][reg] + bsv;
      tacc[mt][reg] = v;
      s[mt][reg] = v; ssq[mt][reg] = v * v;
    }
  #pragma unroll
  for (int mk = 1; mk <= 8; mk <<= 1) {
    #pragma unroll
    for (int mt = 0; mt < 2; mt++)
      #pragma unroll
      for (int reg = 0; reg < 4; reg++) {
        s[mt][reg]   += __shfl_xor(s[mt][reg],   mk);
        ssq[mt][reg] += __shfl_xor(ssq[mt][reg], mk);
      }
  }
  if (col == 0) {
    #pragma unroll
    for (int mt = 0; mt < 2; mt++)
      #pragma unroll
      for (int reg = 0; reg < 4; reg++) {
        red_s[wv][mt][quad * 4 + reg][0] = s[mt][reg];
        red_s[wv][mt][quad * 4 + reg][1] = ssq[mt][reg];
      }
  }
  __syncthreads();
  float mu[2][4], rstd[2][4];
  #pragma unroll
  for (int mt = 0; mt < 2; mt++)
    #pragma unroll
    for (int reg = 0; reg < 4; reg++) {
      float st = 0.f, sst = 0.f;
      #pragma unroll
      for (int w = 0; w < 8; w++) {
        st  += red_s[w][mt][quad * 4 + reg][0];
        sst += red_s[w][mt][quad * 4 + reg][1];
      }
      mu[mt][reg] = st * (1.f / 128.f);
      const float var = sst * (1.f / 128.f) - mu[mt][reg] * mu[mt][reg];
      rstd[mt][reg] = rsqrtf(var + 1e-5f);
    }
  // LN + ReLU + column max over 16 rows of each mtile
  float cm[2];
  #pragma unroll
  for (int mt = 0; mt < 2; mt++) {
    float mx = 0.f;   // ReLU floor
    #pragma unroll
    for (int reg = 0; reg < 4; reg++) {
      float v = (tacc[mt][reg] - mu[mt][reg]) * rstd[mt][reg] * gg + lb;
      v = fmaxf(v, 0.f);
      mx = fmaxf(mx, v);
    }
    cm[mt] = mx;
  }
  #pragma unroll
  for (int mt = 0; mt < 2; mt++) {
    cm[mt] = fmaxf(cm[mt], __shfl_xor(cm[mt], 16));
    cm[mt] = fmaxf(cm[mt], __shfl_xor(cm[mt], 32));
  }
  __syncthreads();   // all red_s reads done (wmax aliases sc_s too)
  if (quad == 0) {
    #pragma unroll
    for (int mt = 0; mt < 2; mt++)
      wmax_s[mt][c] = cm[mt];
  }
  __syncthreads();

  // pooled = max over both row halves; grid-reordered out write
  if (t < 128) {
    const int cc = t;
    const float mx = fmaxf(wmax_s[0][cc], wmax_s[1][cc]);
    pooled_s[cc] = mx;                 // overwrites dead red_s region
    const int mm = g >> 6, nn = (g >> 3) & 7, tt2 = g & 7;
    const int opos = tt2 * 64 + nn * 8 + mm;
    out_all[((size_t)b * G_ + opos) * D_ + cc] = mx;
  }
  __syncthreads();

  // scatter pooled to every point (for_ret); 256 threads, 16 floats each
  if (t < 256) {
    const int p = t >> 3, sg = t & 7;
    const int pid = groups[(b << 14) + g * KP + p];
    float* dst = out_all + (size_t)BB * G_ * D_
               + ((size_t)(b << 14) + (size_t)pid) * D_ + sg * 16;
    #pragma unroll
    for (int u = 0; u < 4; u++)
      *(float4*)(dst + u * 4) = *(const float4*)&pooled_s[sg * 16 + u * 4];
  }
}

// ---------------------------------------------------------------------------
extern "C" void kernel_launch(void* const* d_in, const int* in_sizes, int n_in,
                              void* d_out, int out_size, void* d_ws, size_t ws_size,
                              hipStream_t stream) {
  const float* inputs  = (const float*)d_in[0];
  const float* coords  = (const float*)d_in[1];
  const float* qkv_w   = (const float*)d_in[2];   // [2,128,384]
  const float* qkv_b   = (const float*)d_in[3];   // [2,384]
  const float* tbl_x   = (const float*)d_in[4];   // [2,3,50,128]
  const float* tbl_y   = (const float*)d_in[5];
  const float* tbl_z   = (const float*)d_in[6];
  const float* trans_w = (const float*)d_in[7];   // [384,128]
  const float* trans_b = (const float*)d_in[8];
  const float* ln_g    = (const float*)d_in[9];
  const float* ln_b    = (const float*)d_in[10];
  const int*   groups  = (const int*)d_in[11];    // [2,512,32] flat

  float* out = (float*)d_out;
  unsigned short* allfrag   = (unsigned short*)d_ws;       // 2*FRAG_S
  unsigned short* transfrag = allfrag + 2 * FRAG_S;        // 96*512
  float* bc  = (float*)(transfrag + 96 * 512);             // 2*544 f32

  // ---- ALL weight prep in one launch ----
  prep_all<<<370, 64, 0, stream>>>(qkv_w, trans_w, qkv_b,
                                   tbl_x, tbl_y, tbl_z,
                                   allfrag, transfrag, bc);

  // ---- whole network, one kernel ----
  mega<<<BB * G_, 512, 0, stream>>>(inputs, coords, groups, allfrag, bc,
                                    transfrag, trans_b, ln_g, ln_b, out);
}

// Round 8
// 146.322 us; speedup vs baseline: 1.0653x; 1.0653x over previous
//
#include <hip/hip_runtime.h>
#include <cstddef>

// Voxel encoder: B=2, N=16384, G=512 voxels x K=32 pts, d=128, S=2 layers.
// Round 21: VGPR-64 CLIFF identified (m69: waves/SIMD halve above 64).
// r13(56)=45.5, r14/15/18(64)=46-47, r20(68)=74, r17(80)=73 --
// Occ x dur constant => same wave-cycles, halved residency. RULE: mega
// MUST stay <=64 VGPR. This round: r18 base + ONE change: merge scores+
// softmax into a wave-local phase. Waves 0-1 each compute 16 FULL rows x
// 32 cols (8 MFMAs), so softmax reduces within the 16-lane quad group
// (shfl_xor 1/2/4/8) -- no cross-wave row dependency -> one barrier per
// layer removed (11->9) + sc_s round-trip gone. P goes to dedicated
// P_s[32][40] (k-region must stay intact for the other wave's k-reads).
// Trans chunk moved BEFORE scores so avu/tgv die first (VGPR peak stays
// in phase A). RULES: min-waves<=2 (r8/r10); <=2 B-frag tiles live (r17);
// 1 voxel/block (r16); no inline-asm cvt_pk (r19); VGPR<=64 (r20).

#define D_   128
#define VSF  0.25f
#define QSF  0.01f
#define LQ   50
#define G_   512
#define KP   32
#define BB   2
#define NP   16384
#define MT   32768
#define SCALE 0.08838834764831845f   // 1/sqrt(128)
#define NT_ALL 34           // 24 qkv tiles + 10 dk tiles (cols 0..543)
#define FRAG_S (NT_ALL * 4 * 64 * 8)   // ushorts per layer frag buffer

using short8 = __attribute__((ext_vector_type(8))) short;
using f32x4  = __attribute__((ext_vector_type(4))) float;

__device__ inline unsigned short f2bf(float x) {
  unsigned u = __builtin_bit_cast(unsigned, x);
  u += 0x7fffu + ((u >> 16) & 1u);      // round-to-nearest-even
  return (unsigned short)(u >> 16);
}
__device__ inline float bu(unsigned short h) {
  return __builtin_bit_cast(float, (unsigned)h << 16);
}
__device__ inline short8 as_short8(uint4 v) {
  union { uint4 u; short8 s; } x; x.u = v; return x.s;
}

// ---------------------------------------------------------------------------
// prep_all: all weight preprocessing in ONE launch. 370 blocks x 64 threads.
// (unchanged from r18)
// ---------------------------------------------------------------------------
__global__ __launch_bounds__(64) void prep_all(
    const float* __restrict__ qkv_w, const float* __restrict__ trans_w,
    const float* __restrict__ qkv_b,
    const float* __restrict__ tbl_x, const float* __restrict__ tbl_y,
    const float* __restrict__ tbl_z,
    unsigned short* __restrict__ allfrag,
    unsigned short* __restrict__ transfrag,
    float* __restrict__ bc)
{
  __shared__ __align__(16) float As[32][132];   // Wk rows   (Wf branch only)
  __shared__ __align__(16) float Ts[16][132];   // T columns (Wf branch only)

  const int blk  = blockIdx.x;
  const int lane = threadIdx.x;

  if (blk >= 192 && blk < 272) {
    // ---- Wf frag blocks: compute Wf[m][c] = sum_e Wk[m][e] * T[e][c] ----
    const int s = (blk - 192) / 40, r = (blk - 192) - s * 40;
    const int snt = r >> 2, ks = r & 3;
    const float* Abase = qkv_w + (size_t)s * 128 * 384 + 128;
    for (int i = lane; i < 32 * 32; i += 64) {
      const int m = i >> 5, q = i & 31;
      float4 v = *(const float4*)(Abase + (size_t)(ks * 32 + m) * 384 + q * 4);
      *(float4*)&As[m][q * 4] = v;
    }
    for (int i = lane; i < 16 * 32; i += 64) {
      const int cl = i >> 5, q = i & 31;
      const int c = snt * 16 + cl;
      float4 v = {0.f, 0.f, 0.f, 0.f};
      if (c < 150) {
        const int axis = c / 50, l = c - axis * 50;
        const float* tb = (axis == 0 ? tbl_x : (axis == 1 ? tbl_y : tbl_z));
        v = *(const float4*)(tb + (((size_t)s * 3 + 1) * LQ + l) * D_ + q * 4);
      }
      *(float4*)&Ts[cl][q * 4] = v;
    }
    __syncthreads();
    const int cl = lane & 15, mb = (lane >> 4) * 8;
    float acc[8];
    #pragma unroll
    for (int m = 0; m < 8; m++) acc[m] = 0.f;
    for (int e = 0; e < 128; e += 4) {
      float4 tv = *(const float4*)&Ts[cl][e];
      #pragma unroll
      for (int m = 0; m < 8; m++) {
        float4 av = *(const float4*)&As[mb + m][e];
        acc[m] += av.x * tv.x;
        acc[m] += av.y * tv.y;
        acc[m] += av.z * tv.z;
        acc[m] += av.w * tv.w;
      }
    }
    unsigned v[4];
    #pragma unroll
    for (int h = 0; h < 4; h++)
      v[h] = f2bf(acc[2 * h]) | ((unsigned)f2bf(acc[2 * h + 1]) << 16);
    uint4 o = {v[0], v[1], v[2], v[3]};
    unsigned short* dst = allfrag + (size_t)s * FRAG_S;
    const int dstidx = (24 + snt) * 4 + ks;
    *(uint4*)(dst + ((size_t)dstidx * 64 + lane) * 8) = o;
    return;
  }

  if (blk >= 368) {
    // ---- bc: [0,384) qkv_b copy; [384,544) = bk @ T from tables ----
    const int s = blk - 368;
    for (int c = lane; c < 544; c += 64) {
      float v;
      if (c < 384) {
        v = qkv_b[s * 384 + c];
      } else {
        const int cc = c - 384;
        float a = 0.f;
        if (cc < 150) {
          const int axis = cc / 50, l = cc - axis * 50;
          const float* tb = (axis == 0 ? tbl_x : (axis == 1 ? tbl_y : tbl_z));
          const float* tr = tb + (((size_t)s * 3 + 1) * LQ + l) * D_;
          const float* bk = qkv_b + (size_t)s * 384 + 128;
          #pragma unroll 4
          for (int e = 0; e < 128; e++) a += bk[e] * tr[e];
        }
        v = a;
      }
      bc[s * 544 + c] = v;
    }
    return;
  }

  // ---- direct frag packing (qkv / trans weights) ----
  const float* B; int ldb, dstidx; unsigned short* dst; int kbase, n;
  if (blk < 192) {
    const int s = blk / 96, r = blk - s * 96;
    const int nt = r >> 2, ks = r & 3;
    B = qkv_w + (size_t)s * 128 * 384; ldb = 384;
    n = nt * 16 + (lane & 15);
    kbase = ks * 32 + ((lane >> 4) * 8);
    dst = allfrag + (size_t)s * FRAG_S;
    dstidx = nt * 4 + ks;
  } else {
    const int r = blk - 272;
    const int nt = r / 12, ks = r - nt * 12;
    B = trans_w; ldb = 128;
    n = nt * 16 + (lane & 15);
    kbase = ks * 32 + ((lane >> 4) * 8);
    dst = transfrag;
    dstidx = nt * 12 + ks;
  }
  unsigned v[4];
  #pragma unroll
  for (int h = 0; h < 4; h++) {
    const float x0 = B[(size_t)(kbase + 2 * h) * ldb + n];
    const float x1 = B[(size_t)(kbase + 2 * h + 1) * ldb + n];
    v[h] = f2bf(x0) | ((unsigned)f2bf(x1) << 16);
  }
  uint4 o = {v[0], v[1], v[2], v[3]};
  *(uint4*)(dst + ((size_t)dstidx * 64 + lane) * 8) = o;
}

// ---------------------------------------------------------------------------
// MEGA: one block (8 waves, 512 threads) per voxel; whole network per voxel.
// qk_s row (stride 424): q/f2 0:128 | k 128:256 | dk 256:416.
// feats_s holds x0, then f1 after layer-0 PV. red/wmax/pooled alias sc_s.
// P lives in dedicated P_s[32][40]. Scores+softmax merged, wave-local
// (waves 0-1 own 16 full rows each).
// ---------------------------------------------------------------------------
__global__ __launch_bounds__(512, 2) void mega(
    const float* __restrict__ inputs,
    const float* __restrict__ coords,
    const int*   __restrict__ groups,
    const unsigned short* __restrict__ allfrag,   // 2 x FRAG_S
    const float* __restrict__ bc,                 // 2 x 544
    const unsigned short* __restrict__ transfrag, // 8 nt x 12 ks
    const float* __restrict__ trans_b, const float* __restrict__ ln_g,
    const float* __restrict__ ln_b,
    float* __restrict__ out_all)
{
  __shared__ __align__(16) unsigned short feats_s[32][136];  // x0, then f1
  __shared__ __align__(16) unsigned short qk_s[32][424];     // q|k|dk; f2->q
  __shared__ __align__(16) unsigned short vT_s[128][40];     // V^T [f][j]
  __shared__ __align__(16) unsigned short P_s[32][40];       // softmax P
  __shared__ __align__(16) float sc_s[32 * 34];   // red/wmax/pooled aliases
  __shared__ float cs[32][4];
  float (*red_s)[2][16][2] = (float (*)[2][16][2])sc_s;      // 2048 B
  float (*wmax_s)[128]     = (float (*)[128])(sc_s + 512);   // 1024 B
  float* pooled_s = sc_s;                                    // 512 B

  const int t   = threadIdx.x;
  const int bid = blockIdx.x;
  const int b   = bid >> 9;
  const int g   = bid & 511;
  const int wv = t >> 6, lane = t & 63, quad = lane >> 4, col = lane & 15;

  // ---- stage feats (gather + fp32->bf16): 16 thr/row, 8 elems each ----
  {
    const int p = t >> 4, sg = t & 15;
    const int pid = groups[(b << 14) + g * KP + p];
    const float* src = inputs + ((size_t)(b << 14) + (size_t)pid) * D_ + sg * 8;
    float4 a0 = *(const float4*)(src);
    float4 a1 = *(const float4*)(src + 4);
    uint4 o0;
    o0.x = f2bf(a0.x) | ((unsigned)f2bf(a0.y) << 16);
    o0.y = f2bf(a0.z) | ((unsigned)f2bf(a0.w) << 16);
    o0.z = f2bf(a1.x) | ((unsigned)f2bf(a1.y) << 16);
    o0.w = f2bf(a1.z) | ((unsigned)f2bf(a1.w) << 16);
    *(uint4*)&feats_s[p][sg * 8] = o0;
  }
  if (t < 32) {
    const int pid = groups[(b << 14) + g * KP + t];
    const float* cp = coords + ((size_t)(b << 14) + (size_t)pid) * 3;
    cs[t][0] = cp[0]; cs[t][1] = cp[1]; cs[t][2] = cp[2];
  }
  __syncthreads();

  // ---- phase-A tile ranges: frag read once per block ----
  const int startsA[8] = {0, 5, 10, 14, 18, 22, 26, 30};
  const int cntsA[8]   = {5, 5, 4, 4, 4, 4, 4, 4};
  const int start = startsA[wv];
  const int cnt   = cntsA[wv];

  // persistent trans accumulators: wave wv owns output cols wv*16..wv*16+15
  f32x4 tacc[2];
  tacc[0] = (f32x4){0.f, 0.f, 0.f, 0.f};
  tacc[1] = (f32x4){0.f, 0.f, 0.f, 0.f};
  const uint4* tf = (const uint4*)transfrag + lane;

  for (int layer = 0; layer < 2; layer++) {
    const uint4* fr = (const uint4*)(allfrag + (size_t)layer * FRAG_S) + lane;
    const float* bcl = bc + layer * 544;

    // A-frags for BOTH row halves; layer 0: x0, layer 1: f1 (same buffer)
    uint4 avu[2][4];
    #pragma unroll
    for (int ks = 0; ks < 4; ks++) {
      avu[0][ks] = *(const uint4*)&feats_s[col][ks * 32 + quad * 8];
      avu[1][ks] = *(const uint4*)&feats_s[16 + col][ks * 32 + quad * 8];
    }

    // Phase A with depth-1 prefetch of next tile's B-frags (tail guarded)
    uint4 bvc[4];
    #pragma unroll
    for (int ks = 0; ks < 4; ks++) bvc[ks] = fr[(start * 4 + ks) * 64];

    for (int u = 0; u < cnt; u++) {
      const bool pf = (u + 1 < cnt);       // wave-uniform
      uint4 bvn[4];
      if (pf) {
        #pragma unroll
        for (int ks = 0; ks < 4; ks++)
          bvn[ks] = fr[((start + u + 1) * 4 + ks) * 64];
      }

      f32x4 a0 = (f32x4){0.f, 0.f, 0.f, 0.f};
      f32x4 a1 = (f32x4){0.f, 0.f, 0.f, 0.f};
      #pragma unroll
      for (int ks = 0; ks < 4; ks++) {
        short8 bv = as_short8(bvc[ks]);
        a0 = __builtin_amdgcn_mfma_f32_16x16x32_bf16(as_short8(avu[0][ks]), bv, a0, 0, 0, 0);
        a1 = __builtin_amdgcn_mfma_f32_16x16x32_bf16(as_short8(avu[1][ks]), bv, a1, 0, 0, 0);
      }
      const int nt = start + u;
      const int cc = nt * 16 + col;
      const float bsv = bcl[cc];
      if (cc >= 256 && cc < 384) {          // V tile -> vT_s[f][j], b64 x2
        const unsigned lo0 = f2bf(a0[0] + bsv) | ((unsigned)f2bf(a0[1] + bsv) << 16);
        const unsigned hi0 = f2bf(a0[2] + bsv) | ((unsigned)f2bf(a0[3] + bsv) << 16);
        uint2 w0 = {lo0, hi0};
        *(uint2*)&vT_s[cc - 256][quad * 4] = w0;
        const unsigned lo1 = f2bf(a1[0] + bsv) | ((unsigned)f2bf(a1[1] + bsv) << 16);
        const unsigned hi1 = f2bf(a1[2] + bsv) | ((unsigned)f2bf(a1[3] + bsv) << 16);
        uint2 w1 = {lo1, hi1};
        *(uint2*)&vT_s[cc - 256][16 + quad * 4] = w1;
      } else {
        const int ccol = (cc < 256) ? cc : cc - 128;   // dk -> 256..415
        #pragma unroll
        for (int reg = 0; reg < 4; reg++) {
          qk_s[quad * 4 + reg][ccol]      = f2bf(a0[reg] + bsv);
          qk_s[16 + quad * 4 + reg][ccol] = f2bf(a1[reg] + bsv);
        }
      }
      if (pf) {
        #pragma unroll
        for (int ks = 0; ks < 4; ks++) bvc[ks] = bvn[ks];
      }
    }
    // prefetch this layer's trans-chunk B-frags; the barrier's vmcnt drain
    // absorbs the latency.
    uint4 tgv[4];
    #pragma unroll
    for (int ks = 0; ks < 4; ks++) tgv[ks] = tf[(wv * 12 + layer * 4 + ks) * 64];
    __syncthreads();

    // trans chunk FIRST (all waves; kills avu+tgv -> VGPR peak stays in A)
    #pragma unroll
    for (int ks = 0; ks < 4; ks++) {
      short8 bv = as_short8(tgv[ks]);
      tacc[0] = __builtin_amdgcn_mfma_f32_16x16x32_bf16(as_short8(avu[0][ks]), bv, tacc[0], 0, 0, 0);
      tacc[1] = __builtin_amdgcn_mfma_f32_16x16x32_bf16(as_short8(avu[1][ks]), bv, tacc[1], 0, 0, 0);
    }

    // merged scores + softmax: waves 0-1 own 16 FULL rows each (32 cols)
    if (wv < 2) {
      const int rb = wv * 16;              // row base
      f32x4 s0 = {0.f, 0.f, 0.f, 0.f};     // cols 0..15
      f32x4 s1 = {0.f, 0.f, 0.f, 0.f};     // cols 16..31
      #pragma unroll
      for (int ks = 0; ks < 4; ks++) {
        short8 qv  = as_short8(*(const uint4*)&qk_s[rb + col][ks * 32 + quad * 8]);
        short8 kv0 = as_short8(*(const uint4*)&qk_s[col][128 + ks * 32 + quad * 8]);
        short8 kv1 = as_short8(*(const uint4*)&qk_s[16 + col][128 + ks * 32 + quad * 8]);
        s0 = __builtin_amdgcn_mfma_f32_16x16x32_bf16(qv, kv0, s0, 0, 0, 0);
        s1 = __builtin_amdgcn_mfma_f32_16x16x32_bf16(qv, kv1, s1, 0, 0, 0);
      }
      // bias + scale + wave-local softmax (rows rb+quad*4+reg; 16-lane quads)
      const int j0 = col, j1 = 16 + col;
      const float c0x = cs[j0][0], c0y = cs[j0][1], c0z = cs[j0][2];
      const float c1x = cs[j1][0], c1y = cs[j1][1], c1z = cs[j1][2];
      #pragma unroll
      for (int reg = 0; reg < 4; reg++) {
        const int i = rb + quad * 4 + reg;
        const unsigned short* dki = &qk_s[i][256];
        // col j0
        float dx = cs[i][0] - c0x, dy = cs[i][1] - c0y, dz = cs[i][2] - c0z;
        int ix = (int)floorf((dx + VSF) / QSF);
        int iy = (int)floorf((dy + VSF) / QSF);
        int iz = (int)floorf((dz + VSF) / QSF);
        ix = ix < 0 ? 0 : (ix > 49 ? 49 : ix);
        iy = iy < 0 ? 0 : (iy > 49 ? 49 : iy);
        iz = iz < 0 ? 0 : (iz > 49 ? 49 : iz);
        float sc0 = (s0[reg] + bu(dki[ix]) + bu(dki[50 + iy]) + bu(dki[100 + iz])) * SCALE;
        // col j1
        dx = cs[i][0] - c1x; dy = cs[i][1] - c1y; dz = cs[i][2] - c1z;
        ix = (int)floorf((dx + VSF) / QSF);
        iy = (int)floorf((dy + VSF) / QSF);
        iz = (int)floorf((dz + VSF) / QSF);
        ix = ix < 0 ? 0 : (ix > 49 ? 49 : ix);
        iy = iy < 0 ? 0 : (iy > 49 ? 49 : iy);
        iz = iz < 0 ? 0 : (iz > 49 ? 49 : iz);
        float sc1 = (s1[reg] + bu(dki[ix]) + bu(dki[50 + iy]) + bu(dki[100 + iz])) * SCALE;
        // row max over 32 cols: lane-local pair max + 16-lane tree
        float m = fmaxf(sc0, sc1);
        m = fmaxf(m, __shfl_xor(m, 1));
        m = fmaxf(m, __shfl_xor(m, 2));
        m = fmaxf(m, __shfl_xor(m, 4));
        m = fmaxf(m, __shfl_xor(m, 8));
        const float e0 = __expf(sc0 - m);
        const float e1 = __expf(sc1 - m);
        float sm = e0 + e1;
        sm += __shfl_xor(sm, 1);
        sm += __shfl_xor(sm, 2);
        sm += __shfl_xor(sm, 4);
        sm += __shfl_xor(sm, 8);
        const float inv = 1.f / sm;
        P_s[i][j0] = f2bf(e0 * inv);
        P_s[i][j1] = f2bf(e1 * inv);
      }
    }
    __syncthreads();

    // PV via MFMA: wave wv does mt=wv&1, ftiles (wv>>1)*2 + {0,1}.
    // layer 0 -> f1 overwrites feats_s; layer 1 -> f2 into qk_s cols 0..127.
    {
      const int mt = wv & 1, ftb = (wv >> 1) * 2;
      unsigned short* dst_base = (layer == 0) ? &feats_s[0][0] : &qk_s[0][0];
      const int dst_ld = (layer == 0) ? 136 : 424;
      short8 pv = as_short8(*(const uint4*)&P_s[mt * 16 + col][quad * 8]);
      #pragma unroll
      for (int u = 0; u < 2; u++) {
        const int ft = ftb + u;
        short8 vv = as_short8(*(const uint4*)&vT_s[ft * 16 + col][quad * 8]);
        f32x4 o = (f32x4){0.f, 0.f, 0.f, 0.f};
        o = __builtin_amdgcn_mfma_f32_16x16x32_bf16(pv, vv, o, 0, 0, 0);
        const int f = ft * 16 + col;
        #pragma unroll
        for (int reg = 0; reg < 4; reg++) {
          const int i = mt * 16 + quad * 4 + reg;
          dst_base[i * dst_ld + f] = f2bf(o[reg]);
        }
      }
    }
    __syncthreads();
  }

  // ---- trans GEMM tail: only the f2 chunk (ks 8..11) remains ----
  const int nt = wv;
  {
    uint4 gv[4];
    #pragma unroll
    for (int ks = 0; ks < 4; ks++) gv[ks] = tf[(nt * 12 + 8 + ks) * 64];
    #pragma unroll
    for (int ks = 0; ks < 4; ks++) {
      short8 bv = as_short8(gv[ks]);
      #pragma unroll
      for (int mt = 0; mt < 2; mt++) {
        short8 av = as_short8(*(const uint4*)&qk_s[mt * 16 + col][ks * 32 + quad * 8]);
        tacc[mt] = __builtin_amdgcn_mfma_f32_16x16x32_bf16(av, bv, tacc[mt], 0, 0, 0);
      }
    }
  }
  // bias + LN partial stats (16 cols per wave, both mtiles)
  const int c = nt * 16 + col;
  const float bsv = trans_b[c], gg = ln_g[c], lb = ln_b[c];
  float s[2][4], ssq[2][4];
  #pragma unroll
  for (int mt = 0; mt < 2; mt++)
    #pragma unroll
    for (int reg = 0; reg < 4; reg++) {
      const float v = tacc[mt][reg] + bsv;
      tacc[mt][reg] = v;
      s[mt][reg] = v; ssq[mt][reg] = v * v;
    }
  #pragma unroll
  for (int mk = 1; mk <= 8; mk <<= 1) {
    #pragma unroll
    for (int mt = 0; mt < 2; mt++)
      #pragma unroll
      for (int reg = 0; reg < 4; reg++) {
        s[mt][reg]   += __shfl_xor(s[mt][reg],   mk);
        ssq[mt][reg] += __shfl_xor(ssq[mt][reg], mk);
      }
  }
  if (col == 0) {
    #pragma unroll
    for (int mt = 0; mt < 2; mt++)
      #pragma unroll
      for (int reg = 0; reg < 4; reg++) {
        red_s[wv][mt][quad * 4 + reg][0] = s[mt][reg];
        red_s[wv][mt][quad * 4 + reg][1] = ssq[mt][reg];
      }
  }
  __syncthreads();
  float mu[2][4], rstd[2][4];
  #pragma unroll
  for (int mt = 0; mt < 2; mt++)
    #pragma unroll
    for (int reg = 0; reg < 4; reg++) {
      float st = 0.f, sst = 0.f;
      #pragma unroll
      for (int w = 0; w < 8; w++) {
        st  += red_s[w][mt][quad * 4 + reg][0];
        sst += red_s[w][mt][quad * 4 + reg][1];
      }
      mu[mt][reg] = st * (1.f / 128.f);
      const float var = sst * (1.f / 128.f) - mu[mt][reg] * mu[mt][reg];
      rstd[mt][reg] = rsqrtf(var + 1e-5f);
    }
  // LN + ReLU + column max over 16 rows of each mtile
  float cm[2];
  #pragma unroll
  for (int mt = 0; mt < 2; mt++) {
    float mx = 0.f;   // ReLU floor
    #pragma unroll
    for (int reg = 0; reg < 4; reg++) {
      float v = (tacc[mt][reg] - mu[mt][reg]) * rstd[mt][reg] * gg + lb;
      v = fmaxf(v, 0.f);
      mx = fmaxf(mx, v);
    }
    cm[mt] = mx;
  }
  #pragma unroll
  for (int mt = 0; mt < 2; mt++) {
    cm[mt] = fmaxf(cm[mt], __shfl_xor(cm[mt], 16));
    cm[mt] = fmaxf(cm[mt], __shfl_xor(cm[mt], 32));
  }
  __syncthreads();   // all red_s reads done (wmax aliases sc_s too)
  if (quad == 0) {
    #pragma unroll
    for (int mt = 0; mt < 2; mt++)
      wmax_s[mt][c] = cm[mt];
  }
  __syncthreads();

  // pooled = max over both row halves; grid-reordered out write
  if (t < 128) {
    const int cc = t;
    const float mx = fmaxf(wmax_s[0][cc], wmax_s[1][cc]);
    pooled_s[cc] = mx;                 // overwrites dead red_s region
    const int mm = g >> 6, nn = (g >> 3) & 7, tt2 = g & 7;
    const int opos = tt2 * 64 + nn * 8 + mm;
    out_all[((size_t)b * G_ + opos) * D_ + cc] = mx;
  }
  __syncthreads();

  // scatter pooled to every point (for_ret); 256 threads, 16 floats each
  if (t < 256) {
    const int p = t >> 3, sg = t & 7;
    const int pid = groups[(b << 14) + g * KP + p];
    float* dst = out_all + (size_t)BB * G_ * D_
               + ((size_t)(b << 14) + (size_t)pid) * D_ + sg * 16;
    #pragma unroll
    for (int u = 0; u < 4; u++)
      *(float4*)(dst + u * 4) = *(const float4*)&pooled_s[sg * 16 + u * 4];
  }
}

// ---------------------------------------------------------------------------
extern "C" void kernel_launch(void* const* d_in, const int* in_sizes, int n_in,
                              void* d_out, int out_size, void* d_ws, size_t ws_size,
                              hipStream_t stream) {
  const float* inputs  = (const float*)d_in[0];
  const float* coords  = (const float*)d_in[1];
  const float* qkv_w   = (const float*)d_in[2];   // [2,128,384]
  const float* qkv_b   = (const float*)d_in[3];   // [2,384]
  const float* tbl_x   = (const float*)d_in[4];   // [2,3,50,128]
  const float* tbl_y   = (const float*)d_in[5];
  const float* tbl_z   = (const float*)d_in[6];
  const float* trans_w = (const float*)d_in[7];   // [384,128]
  const float* trans_b = (const float*)d_in[8];
  const float* ln_g    = (const float*)d_in[9];
  const float* ln_b    = (const float*)d_in[10];
  const int*   groups  = (const int*)d_in[11];    // [2,512,32] flat

  float* out = (float*)d_out;
  unsigned short* allfrag   = (unsigned short*)d_ws;       // 2*FRAG_S
  unsigned short* transfrag = allfrag + 2 * FRAG_S;        // 96*512
  float* bc  = (float*)(transfrag + 96 * 512);             // 2*544 f32

  // ---- ALL weight prep in one launch ----
  prep_all<<<370, 64, 0, stream>>>(qkv_w, trans_w, qkv_b,
                                   tbl_x, tbl_y, tbl_z,
                                   allfrag, transfrag, bc);

  // ---- whole network, one kernel ----
  mega<<<BB * G_, 512, 0, stream>>>(inputs, coords, groups, allfrag, bc,
                                    transfrag, trans_b, ln_g, ln_b, out);
}

// Round 9
// 140.582 us; speedup vs baseline: 1.1088x; 1.0408x over previous
//
#include <hip/hip_runtime.h>
#include <cstddef>

// Voxel encoder: B=2, N=16384, G=512 voxels x K=32 pts, d=128, S=2 layers.
// Round 22: CONSOLIDATION at measured optimum (= r15, best total 139.8us).
// Falsification ledger: LDS diet r14 null; dual-voxel r16 -7%; pair-ILP
// r17 -55% (VGPR 80); idx-precompute r20 -57% (VGPR 68 -- the >64 VGPR
// cliff halves waves/SIMD, m69); cvt_pk r19 incorrect; scores+softmax
// merge r21 -11% (work concentration in 2 waves). sc_s stride 33 vs 34:
// bank-conflict counter bit-identical -> conflicts are the phase-A ushort
// scatter writes, ~6% of cycles, not a lever. Mega floor ~46.6us at
// VGPR<=64; remaining non-mega time is harness workspace poison (45.5us)
// + launch overhead. RULES: VGPR<=64 (r20); 1 voxel/block (r16); <=2
// B-frag tiles live (r17); no inline-asm cvt_pk (r19); min-waves<=2 (r8).

#define D_   128
#define VSF  0.25f
#define QSF  0.01f
#define LQ   50
#define G_   512
#define KP   32
#define BB   2
#define NP   16384
#define MT   32768
#define SCALE 0.08838834764831845f   // 1/sqrt(128)
#define NT_ALL 34           // 24 qkv tiles + 10 dk tiles (cols 0..543)
#define FRAG_S (NT_ALL * 4 * 64 * 8)   // ushorts per layer frag buffer

using short8 = __attribute__((ext_vector_type(8))) short;
using f32x4  = __attribute__((ext_vector_type(4))) float;

__device__ inline unsigned short f2bf(float x) {
  unsigned u = __builtin_bit_cast(unsigned, x);
  u += 0x7fffu + ((u >> 16) & 1u);      // round-to-nearest-even
  return (unsigned short)(u >> 16);
}
__device__ inline float bu(unsigned short h) {
  return __builtin_bit_cast(float, (unsigned)h << 16);
}
__device__ inline short8 as_short8(uint4 v) {
  union { uint4 u; short8 s; } x; x.u = v; return x.s;
}

// ---------------------------------------------------------------------------
// prep_all: all weight preprocessing in ONE launch. 370 blocks x 64 threads.
//   blk   0..191: qkv-weight frags (direct from qkv_w)
//   blk 192..271: Wf frags, Wf = Wk @ T computed on the fly (LDS-staged)
//   blk 272..367: trans-weight frags (direct from trans_w)
//   blk 368..369: combined bias bc (qkv_b | bk @ T, direct from tables)
// ---------------------------------------------------------------------------
__global__ __launch_bounds__(64) void prep_all(
    const float* __restrict__ qkv_w, const float* __restrict__ trans_w,
    const float* __restrict__ qkv_b,
    const float* __restrict__ tbl_x, const float* __restrict__ tbl_y,
    const float* __restrict__ tbl_z,
    unsigned short* __restrict__ allfrag,
    unsigned short* __restrict__ transfrag,
    float* __restrict__ bc)
{
  __shared__ __align__(16) float As[32][132];   // Wk rows   (Wf branch only)
  __shared__ __align__(16) float Ts[16][132];   // T columns (Wf branch only)

  const int blk  = blockIdx.x;
  const int lane = threadIdx.x;

  if (blk >= 192 && blk < 272) {
    // ---- Wf frag blocks: compute Wf[m][c] = sum_e Wk[m][e] * T[e][c] ----
    const int s = (blk - 192) / 40, r = (blk - 192) - s * 40;
    const int snt = r >> 2, ks = r & 3;
    // stage Wk rows m = ks*32 .. ks*32+31 (e contiguous in qkv_w row)
    const float* Abase = qkv_w + (size_t)s * 128 * 384 + 128;
    for (int i = lane; i < 32 * 32; i += 64) {
      const int m = i >> 5, q = i & 31;
      float4 v = *(const float4*)(Abase + (size_t)(ks * 32 + m) * 384 + q * 4);
      *(float4*)&As[m][q * 4] = v;
    }
    // stage T columns c = snt*16 .. snt*16+15 (e contiguous in table row)
    for (int i = lane; i < 16 * 32; i += 64) {
      const int cl = i >> 5, q = i & 31;
      const int c = snt * 16 + cl;
      float4 v = {0.f, 0.f, 0.f, 0.f};
      if (c < 150) {
        const int axis = c / 50, l = c - axis * 50;
        const float* tb = (axis == 0 ? tbl_x : (axis == 1 ? tbl_y : tbl_z));
        v = *(const float4*)(tb + (((size_t)s * 3 + 1) * LQ + l) * D_ + q * 4);
      }
      *(float4*)&Ts[cl][q * 4] = v;
    }
    __syncthreads();
    const int cl = lane & 15, mb = (lane >> 4) * 8;
    float acc[8];
    #pragma unroll
    for (int m = 0; m < 8; m++) acc[m] = 0.f;
    for (int e = 0; e < 128; e += 4) {
      float4 tv = *(const float4*)&Ts[cl][e];
      #pragma unroll
      for (int m = 0; m < 8; m++) {
        float4 av = *(const float4*)&As[mb + m][e];
        // sequential adds: keep e-ascending fp32 order (bitwise == old path)
        acc[m] += av.x * tv.x;
        acc[m] += av.y * tv.y;
        acc[m] += av.z * tv.z;
        acc[m] += av.w * tv.w;
      }
    }
    unsigned v[4];
    #pragma unroll
    for (int h = 0; h < 4; h++)
      v[h] = f2bf(acc[2 * h]) | ((unsigned)f2bf(acc[2 * h + 1]) << 16);
    uint4 o = {v[0], v[1], v[2], v[3]};
    unsigned short* dst = allfrag + (size_t)s * FRAG_S;
    const int dstidx = (24 + snt) * 4 + ks;
    *(uint4*)(dst + ((size_t)dstidx * 64 + lane) * 8) = o;
    return;
  }

  if (blk >= 368) {
    // ---- bc: [0,384) qkv_b copy; [384,544) = bk @ T from tables ----
    const int s = blk - 368;
    for (int c = lane; c < 544; c += 64) {
      float v;
      if (c < 384) {
        v = qkv_b[s * 384 + c];
      } else {
        const int cc = c - 384;
        float a = 0.f;
        if (cc < 150) {
          const int axis = cc / 50, l = cc - axis * 50;
          const float* tb = (axis == 0 ? tbl_x : (axis == 1 ? tbl_y : tbl_z));
          const float* tr = tb + (((size_t)s * 3 + 1) * LQ + l) * D_;
          const float* bk = qkv_b + (size_t)s * 384 + 128;
          #pragma unroll 4
          for (int e = 0; e < 128; e++) a += bk[e] * tr[e];
        }
        v = a;
      }
      bc[s * 544 + c] = v;
    }
    return;
  }

  // ---- direct frag packing (qkv / trans weights) ----
  const float* B; int ldb, dstidx; unsigned short* dst; int kbase, n;
  if (blk < 192) {
    const int s = blk / 96, r = blk - s * 96;
    const int nt = r >> 2, ks = r & 3;
    B = qkv_w + (size_t)s * 128 * 384; ldb = 384;
    n = nt * 16 + (lane & 15);
    kbase = ks * 32 + ((lane >> 4) * 8);
    dst = allfrag + (size_t)s * FRAG_S;
    dstidx = nt * 4 + ks;
  } else {
    const int r = blk - 272;
    const int nt = r / 12, ks = r - nt * 12;
    B = trans_w; ldb = 128;
    n = nt * 16 + (lane & 15);
    kbase = ks * 32 + ((lane >> 4) * 8);
    dst = transfrag;
    dstidx = nt * 12 + ks;
  }
  unsigned v[4];
  #pragma unroll
  for (int h = 0; h < 4; h++) {
    const float x0 = B[(size_t)(kbase + 2 * h) * ldb + n];
    const float x1 = B[(size_t)(kbase + 2 * h + 1) * ldb + n];
    v[h] = f2bf(x0) | ((unsigned)f2bf(x1) << 16);
  }
  uint4 o = {v[0], v[1], v[2], v[3]};
  *(uint4*)(dst + ((size_t)dstidx * 64 + lane) * 8) = o;
}

// ---------------------------------------------------------------------------
// MEGA: one block (8 waves, 512 threads) per voxel; whole network per voxel.
// qk_s row (stride 424): q/f2 0:128 | k,then P 128:256 | dk 256:416.
// feats_s holds x0, then f1 after layer-0 PV (trans chunk0 consumed x0 from
// the avu regs before the overwrite). red/wmax/pooled alias sc_s.
// ---------------------------------------------------------------------------
__global__ __launch_bounds__(512, 2) void mega(
    const float* __restrict__ inputs,
    const float* __restrict__ coords,
    const int*   __restrict__ groups,
    const unsigned short* __restrict__ allfrag,   // 2 x FRAG_S
    const float* __restrict__ bc,                 // 2 x 544
    const unsigned short* __restrict__ transfrag, // 8 nt x 12 ks
    const float* __restrict__ trans_b, const float* __restrict__ ln_g,
    const float* __restrict__ ln_b,
    float* __restrict__ out_all)
{
  __shared__ __align__(16) unsigned short feats_s[32][136];  // x0, then f1
  __shared__ __align__(16) unsigned short qk_s[32][424];     // q|k/P|dk; f2->q
  __shared__ __align__(16) unsigned short vT_s[128][40];     // V^T [f][j]
  __shared__ __align__(16) float sc_s[32 * 33];
  __shared__ float cs[32][4];
  // aliases into sc_s (scores dead after the last softmax):
  float (*red_s)[2][16][2] = (float (*)[2][16][2])sc_s;      // 2048 B
  float (*wmax_s)[128]     = (float (*)[128])(sc_s + 512);   // 1024 B
  float* pooled_s = sc_s;                                    // 512 B

  const int t   = threadIdx.x;
  const int bid = blockIdx.x;
  const int b   = bid >> 9;
  const int g   = bid & 511;
  const int wv = t >> 6, lane = t & 63, quad = lane >> 4, col = lane & 15;

  // ---- stage feats (gather + fp32->bf16): 16 thr/row, 8 elems each ----
  {
    const int p = t >> 4, sg = t & 15;
    const int pid = groups[(b << 14) + g * KP + p];
    const float* src = inputs + ((size_t)(b << 14) + (size_t)pid) * D_ + sg * 8;
    float4 a0 = *(const float4*)(src);
    float4 a1 = *(const float4*)(src + 4);
    uint4 o0;
    o0.x = f2bf(a0.x) | ((unsigned)f2bf(a0.y) << 16);
    o0.y = f2bf(a0.z) | ((unsigned)f2bf(a0.w) << 16);
    o0.z = f2bf(a1.x) | ((unsigned)f2bf(a1.y) << 16);
    o0.w = f2bf(a1.z) | ((unsigned)f2bf(a1.w) << 16);
    *(uint4*)&feats_s[p][sg * 8] = o0;
  }
  if (t < 32) {
    const int pid = groups[(b << 14) + g * KP + t];
    const float* cp = coords + ((size_t)(b << 14) + (size_t)pid) * 3;
    cs[t][0] = cp[0]; cs[t][1] = cp[1]; cs[t][2] = cp[2];
  }
  __syncthreads();

  // ---- phase-A tile ranges: frag read once per block ----
  const int startsA[8] = {0, 5, 10, 14, 18, 22, 26, 30};
  const int cntsA[8]   = {5, 5, 4, 4, 4, 4, 4, 4};
  const int start = startsA[wv];
  const int cnt   = cntsA[wv];

  // persistent trans accumulators: wave wv owns output cols wv*16..wv*16+15
  f32x4 tacc[2];
  tacc[0] = (f32x4){0.f, 0.f, 0.f, 0.f};
  tacc[1] = (f32x4){0.f, 0.f, 0.f, 0.f};
  const uint4* tf = (const uint4*)transfrag + lane;

  for (int layer = 0; layer < 2; layer++) {
    const uint4* fr = (const uint4*)(allfrag + (size_t)layer * FRAG_S) + lane;
    const float* bcl = bc + layer * 544;

    // A-frags for BOTH row halves; layer 0: x0, layer 1: f1 (same buffer)
    uint4 avu[2][4];
    #pragma unroll
    for (int ks = 0; ks < 4; ks++) {
      avu[0][ks] = *(const uint4*)&feats_s[col][ks * 32 + quad * 8];
      avu[1][ks] = *(const uint4*)&feats_s[16 + col][ks * 32 + quad * 8];
    }

    // Phase A with depth-1 prefetch of next tile's B-frags
    uint4 bvc[4];
    #pragma unroll
    for (int ks = 0; ks < 4; ks++) bvc[ks] = fr[(start * 4 + ks) * 64];

    for (int u = 0; u < cnt; u++) {
      const int ntn = start + ((u + 1 < cnt) ? (u + 1) : u);
      uint4 bvn[4];
      #pragma unroll
      for (int ks = 0; ks < 4; ks++) bvn[ks] = fr[(ntn * 4 + ks) * 64];

      f32x4 a0 = (f32x4){0.f, 0.f, 0.f, 0.f};
      f32x4 a1 = (f32x4){0.f, 0.f, 0.f, 0.f};
      #pragma unroll
      for (int ks = 0; ks < 4; ks++) {
        short8 bv = as_short8(bvc[ks]);
        a0 = __builtin_amdgcn_mfma_f32_16x16x32_bf16(as_short8(avu[0][ks]), bv, a0, 0, 0, 0);
        a1 = __builtin_amdgcn_mfma_f32_16x16x32_bf16(as_short8(avu[1][ks]), bv, a1, 0, 0, 0);
      }
      const int nt = start + u;
      const int cc = nt * 16 + col;
      const float bsv = bcl[cc];
      if (cc >= 256 && cc < 384) {          // V tile -> vT_s[f][j], b64 x2
        const unsigned lo0 = f2bf(a0[0] + bsv) | ((unsigned)f2bf(a0[1] + bsv) << 16);
        const unsigned hi0 = f2bf(a0[2] + bsv) | ((unsigned)f2bf(a0[3] + bsv) << 16);
        uint2 w0 = {lo0, hi0};
        *(uint2*)&vT_s[cc - 256][quad * 4] = w0;
        const unsigned lo1 = f2bf(a1[0] + bsv) | ((unsigned)f2bf(a1[1] + bsv) << 16);
        const unsigned hi1 = f2bf(a1[2] + bsv) | ((unsigned)f2bf(a1[3] + bsv) << 16);
        uint2 w1 = {lo1, hi1};
        *(uint2*)&vT_s[cc - 256][16 + quad * 4] = w1;
      } else {
        const int ccol = (cc < 256) ? cc : cc - 128;   // dk -> 256..405
        #pragma unroll
        for (int reg = 0; reg < 4; reg++) {
          qk_s[quad * 4 + reg][ccol]      = f2bf(a0[reg] + bsv);
          qk_s[16 + quad * 4 + reg][ccol] = f2bf(a1[reg] + bsv);
        }
      }
      #pragma unroll
      for (int ks = 0; ks < 4; ks++) bvc[ks] = bvn[ks];
    }
    // prefetch this layer's trans-chunk B-frags; the barrier's vmcnt drain
    // absorbs the latency.
    uint4 tgv[4];
    #pragma unroll
    for (int ks = 0; ks < 4; ks++) tgv[ks] = tf[(wv * 12 + layer * 4 + ks) * 64];
    __syncthreads();

    // scores via MFMA from LDS frags (waves 0..3)
    if (wv < 4) {
      const int ihalf = wv >> 1, jhalf = wv & 1;
      f32x4 sacc = {0.f, 0.f, 0.f, 0.f};
      #pragma unroll
      for (int ks = 0; ks < 4; ks++) {
        short8 qv = as_short8(*(const uint4*)&qk_s[ihalf * 16 + col][ks * 32 + quad * 8]);
        short8 kv = as_short8(*(const uint4*)&qk_s[jhalf * 16 + col][128 + ks * 32 + quad * 8]);
        sacc = __builtin_amdgcn_mfma_f32_16x16x32_bf16(qv, kv, sacc, 0, 0, 0);
      }
      const int j = jhalf * 16 + col;
      const float cjx = cs[j][0], cjy = cs[j][1], cjz = cs[j][2];
      #pragma unroll
      for (int reg = 0; reg < 4; reg++) {
        const int i = ihalf * 16 + quad * 4 + reg;
        const float dx = cs[i][0] - cjx;
        const float dy = cs[i][1] - cjy;
        const float dz = cs[i][2] - cjz;
        int ix = (int)floorf((dx + VSF) / QSF);
        int iy = (int)floorf((dy + VSF) / QSF);
        int iz = (int)floorf((dz + VSF) / QSF);
        ix = ix < 0 ? 0 : (ix > 49 ? 49 : ix);
        iy = iy < 0 ? 0 : (iy > 49 ? 49 : iy);
        iz = iz < 0 ? 0 : (iz > 49 ? 49 : iz);
        const unsigned short* dki = &qk_s[i][256];
        const float biasv = bu(dki[ix]) + bu(dki[50 + iy]) + bu(dki[100 + iz]);
        sc_s[i * 33 + j] = (sacc[reg] + biasv) * SCALE;
      }
    }
    // trans chunk (k-block = this layer's A operand), reusing live avu regs.
    // Waves 4..7 run this in their scores-idle window.
    #pragma unroll
    for (int ks = 0; ks < 4; ks++) {
      short8 bv = as_short8(tgv[ks]);
      tacc[0] = __builtin_amdgcn_mfma_f32_16x16x32_bf16(as_short8(avu[0][ks]), bv, tacc[0], 0, 0, 0);
      tacc[1] = __builtin_amdgcn_mfma_f32_16x16x32_bf16(as_short8(avu[1][ks]), bv, tacc[1], 0, 0, 0);
    }
    __syncthreads();

    // softmax: 8 threads per row (t<256); emit bf16 P over dead k cols 128..159
    if (t < 256) {
      const int p = t >> 3, sg = t & 7;
      float vals[4];
      float lm = -1e30f;
      #pragma unroll
      for (int u = 0; u < 4; u++) {
        vals[u] = sc_s[p * 33 + sg + u * 8];
        lm = fmaxf(lm, vals[u]);
      }
      lm = fmaxf(lm, __shfl_xor(lm, 1));
      lm = fmaxf(lm, __shfl_xor(lm, 2));
      lm = fmaxf(lm, __shfl_xor(lm, 4));
      float ls = 0.f;
      #pragma unroll
      for (int u = 0; u < 4; u++) { vals[u] = __expf(vals[u] - lm); ls += vals[u]; }
      ls += __shfl_xor(ls, 1);
      ls += __shfl_xor(ls, 2);
      ls += __shfl_xor(ls, 4);
      const float inv = 1.f / ls;
      #pragma unroll
      for (int u = 0; u < 4; u++)
        qk_s[p][128 + sg + u * 8] = f2bf(vals[u] * inv);
    }
    __syncthreads();

    // PV via MFMA: wave wv does mt=wv&1, ftiles (wv>>1)*2 + {0,1}.
    // layer 0 -> f1 overwrites feats_s; layer 1 -> f2 into qk_s cols 0..127.
    {
      const int mt = wv & 1, ftb = (wv >> 1) * 2;
      unsigned short* dst_base = (layer == 0) ? &feats_s[0][0] : &qk_s[0][0];
      const int dst_ld = (layer == 0) ? 136 : 424;
      short8 pv = as_short8(*(const uint4*)&qk_s[mt * 16 + col][128 + quad * 8]);
      #pragma unroll
      for (int u = 0; u < 2; u++) {
        const int ft = ftb + u;
        short8 vv = as_short8(*(const uint4*)&vT_s[ft * 16 + col][quad * 8]);
        f32x4 o = (f32x4){0.f, 0.f, 0.f, 0.f};
        o = __builtin_amdgcn_mfma_f32_16x16x32_bf16(pv, vv, o, 0, 0, 0);
        const int f = ft * 16 + col;
        #pragma unroll
        for (int reg = 0; reg < 4; reg++) {
          const int i = mt * 16 + quad * 4 + reg;
          dst_base[i * dst_ld + f] = f2bf(o[reg]);
        }
      }
    }
    __syncthreads();
  }

  // ---- trans GEMM tail: only the f2 chunk (ks 8..11) remains ----
  const int nt = wv;
  {
    uint4 gv[4];
    #pragma unroll
    for (int ks = 0; ks < 4; ks++) gv[ks] = tf[(nt * 12 + 8 + ks) * 64];
    #pragma unroll
    for (int ks = 0; ks < 4; ks++) {
      short8 bv = as_short8(gv[ks]);
      #pragma unroll
      for (int mt = 0; mt < 2; mt++) {
        short8 av = as_short8(*(const uint4*)&qk_s[mt * 16 + col][ks * 32 + quad * 8]);
        tacc[mt] = __builtin_amdgcn_mfma_f32_16x16x32_bf16(av, bv, tacc[mt], 0, 0, 0);
      }
    }
  }
  // bias + LN partial stats (16 cols per wave, both mtiles)
  const int c = nt * 16 + col;
  const float bsv = trans_b[c], gg = ln_g[c], lb = ln_b[c];
  float s[2][4], ssq[2][4];
  #pragma unroll
  for (int mt = 0; mt < 2; mt++)
    #pragma unroll
    for (int reg = 0; reg < 4; reg++) {
      const float v = tacc[mt][reg] + bsv;
      tacc[mt][reg] = v;
      s[mt][reg] = v; ssq[mt][reg] = v * v;
    }
  #pragma unroll
  for (int mk = 1; mk <= 8; mk <<= 1) {
    #pragma unroll
    for (int mt = 0; mt < 2; mt++)
      #pragma unroll
      for (int reg = 0; reg < 4; reg++) {
        s[mt][reg]   += __shfl_xor(s[mt][reg],   mk);
        ssq[mt][reg] += __shfl_xor(ssq[mt][reg], mk);
      }
  }
  if (col == 0) {
    #pragma unroll
    for (int mt = 0; mt < 2; mt++)
      #pragma unroll
      for (int reg = 0; reg < 4; reg++) {
        red_s[wv][mt][quad * 4 + reg][0] = s[mt][reg];
        red_s[wv][mt][quad * 4 + reg][1] = ssq[mt][reg];
      }
  }
  __syncthreads();
  float mu[2][4], rstd[2][4];
  #pragma unroll
  for (int mt = 0; mt < 2; mt++)
    #pragma unroll
    for (int reg = 0; reg < 4; reg++) {
      float st = 0.f, sst = 0.f;
      #pragma unroll
      for (int w = 0; w < 8; w++) {
        st  += red_s[w][mt][quad * 4 + reg][0];
        sst += red_s[w][mt][quad * 4 + reg][1];
      }
      mu[mt][reg] = st * (1.f / 128.f);
      const float var = sst * (1.f / 128.f) - mu[mt][reg] * mu[mt][reg];
      rstd[mt][reg] = rsqrtf(var + 1e-5f);
    }
  // LN + ReLU + column max over 16 rows of each mtile
  float cm[2];
  #pragma unroll
  for (int mt = 0; mt < 2; mt++) {
    float mx = 0.f;   // ReLU floor
    #pragma unroll
    for (int reg = 0; reg < 4; reg++) {
      float v = (tacc[mt][reg] - mu[mt][reg]) * rstd[mt][reg] * gg + lb;
      v = fmaxf(v, 0.f);
      mx = fmaxf(mx, v);
    }
    cm[mt] = mx;
  }
  #pragma unroll
  for (int mt = 0; mt < 2; mt++) {
    cm[mt] = fmaxf(cm[mt], __shfl_xor(cm[mt], 16));
    cm[mt] = fmaxf(cm[mt], __shfl_xor(cm[mt], 32));
  }
  __syncthreads();   // all red_s reads done (wmax aliases sc_s too)
  if (quad == 0) {
    #pragma unroll
    for (int mt = 0; mt < 2; mt++)
      wmax_s[mt][c] = cm[mt];
  }
  __syncthreads();

  // pooled = max over both row halves; grid-reordered out write
  if (t < 128) {
    const int cc = t;
    const float mx = fmaxf(wmax_s[0][cc], wmax_s[1][cc]);
    pooled_s[cc] = mx;
    const int mm = g >> 6, nn = (g >> 3) & 7, tt2 = g & 7;
    const int opos = tt2 * 64 + nn * 8 + mm;
    out_all[((size_t)b * G_ + opos) * D_ + cc] = mx;
  }
  __syncthreads();

  // scatter pooled to every point (for_ret); 256 threads, 16 floats each
  if (t < 256) {
    const int p = t >> 3, sg = t & 7;
    const int pid = groups[(b << 14) + g * KP + p];
    float* dst = out_all + (size_t)BB * G_ * D_
               + ((size_t)(b << 14) + (size_t)pid) * D_ + sg * 16;
    #pragma unroll
    for (int u = 0; u < 4; u++)
      *(float4*)(dst + u * 4) = *(const float4*)&pooled_s[sg * 16 + u * 4];
  }
}

// ---------------------------------------------------------------------------
extern "C" void kernel_launch(void* const* d_in, const int* in_sizes, int n_in,
                              void* d_out, int out_size, void* d_ws, size_t ws_size,
                              hipStream_t stream) {
  const float* inputs  = (const float*)d_in[0];
  const float* coords  = (const float*)d_in[1];
  const float* qkv_w   = (const float*)d_in[2];   // [2,128,384]
  const float* qkv_b   = (const float*)d_in[3];   // [2,384]
  const float* tbl_x   = (const float*)d_in[4];   // [2,3,50,128]
  const float* tbl_y   = (const float*)d_in[5];
  const float* tbl_z   = (const float*)d_in[6];
  const float* trans_w = (const float*)d_in[7];   // [384,128]
  const float* trans_b = (const float*)d_in[8];
  const float* ln_g    = (const float*)d_in[9];
  const float* ln_b    = (const float*)d_in[10];
  const int*   groups  = (const int*)d_in[11];    // [2,512,32] flat

  float* out = (float*)d_out;
  unsigned short* allfrag   = (unsigned short*)d_ws;       // 2*FRAG_S
  unsigned short* transfrag = allfrag + 2 * FRAG_S;        // 96*512
  float* bc  = (float*)(transfrag + 96 * 512);             // 2*544 f32

  // ---- ALL weight prep in one launch ----
  prep_all<<<370, 64, 0, stream>>>(qkv_w, trans_w, qkv_b,
                                   tbl_x, tbl_y, tbl_z,
                                   allfrag, transfrag, bc);

  // ---- whole network, one kernel ----
  mega<<<BB * G_, 512, 0, stream>>>(inputs, coords, groups, allfrag, bc,
                                    transfrag, trans_b, ln_g, ln_b, out);
}